// Round 15
// baseline (206.674 us; speedup 1.0000x reference)
//
#include <hip/hip_runtime.h>
#include <stdint.h>

// CriticNetwork (R15 = R14 + fix):
//   value[b,i,m] = ve[i] + (sv[i] + w[i,m]*dv[m])/64
//   weights5[b,i,m,j] = w[b,i,j]
// scores[i,j] = oa_i M oa_j^T, M[d][e] = sum_c Wk[c,d] Wq[c,e]  (f32, setup).
// R14 bug: s_u/s_g load pattern assumed 512 threads; at 256 threads
// s_g[112..127] was never written -> ve wrong by O(0.3). Fixed with a
// strided cooperative load. Structure otherwise identical to R14:
// 4096 blocks x 256 thr, ~19 KB LDS, 3 barriers, shuffle reductions.

#define BB 128
#define NN 64
#define OBSD 128
#define ACTD 16
#define DD 144
#define RSW 146   // u16 LDS stride: dword stride 73 (odd) -> conflict-free

typedef float f32x4 __attribute__((ext_vector_type(4)));

// ws floats: M[144][144] at 0, u[144] at U_OFF, g[128] at G_OFF
#define U_OFF 20736
#define G_OFF 20880

__device__ __forceinline__ unsigned short bf1(float x) {
  unsigned u = __float_as_uint(x);
  return (unsigned short)((u + 0x7fffu + ((u >> 16) & 1u)) >> 16);
}
__device__ __forceinline__ unsigned int pack_bf2(float x, float y) {
  return (unsigned)bf1(x) | ((unsigned)bf1(y) << 16);
}
__device__ __forceinline__ float bf2f(unsigned short s) {
  return __uint_as_float(((unsigned)s) << 16);
}

// ---------------- setup: M (f32) + u + g ----------------
__global__ __launch_bounds__(256) void critic_setup(
    const float* __restrict__ Wk, const float* __restrict__ Wq,
    const float* __restrict__ Wv, const float* __restrict__ Wenc,
    const float* __restrict__ Wfin, float* __restrict__ ws)
{
  const int bid = blockIdx.x, t = threadIdx.x;
  if (bid < DD) {                        // M[d][e] = sum_c Wk[c,d] Wq[c,e]
    const int d = bid;
    if (t < DD) {
      float a0=0.f,a1=0.f,a2=0.f,a3=0.f;
      for (int c = 0; c < 128; c += 4) {
        a0 += Wk[(c+0)*DD + d] * Wq[(c+0)*DD + t];
        a1 += Wk[(c+1)*DD + d] * Wq[(c+1)*DD + t];
        a2 += Wk[(c+2)*DD + d] * Wq[(c+2)*DD + t];
        a3 += Wk[(c+3)*DD + d] * Wq[(c+3)*DD + t];
      }
      ws[d * DD + t] = (a0+a1)+(a2+a3);
    }
  } else if (bid == DD) {                // u[t] = sum_c Wv[c,t] Wfin[128+c]
    if (t < DD) {
      float a0=0.f,a1=0.f,a2=0.f,a3=0.f;
      for (int c = 0; c < 128; c += 4) {
        a0 += Wv[(c+0)*DD + t] * Wfin[OBSD + c + 0];
        a1 += Wv[(c+1)*DD + t] * Wfin[OBSD + c + 1];
        a2 += Wv[(c+2)*DD + t] * Wfin[OBSD + c + 2];
        a3 += Wv[(c+3)*DD + t] * Wfin[OBSD + c + 3];
      }
      ws[U_OFF + t] = (a0+a1)+(a2+a3);
    }
  } else {                               // g[d] = sum_c Wenc[c,d] Wfin[c]
    if (t < OBSD) {
      float a0=0.f,a1=0.f,a2=0.f,a3=0.f;
      for (int c = 0; c < 128; c += 4) {
        a0 += Wenc[(c+0)*OBSD + t] * Wfin[c + 0];
        a1 += Wenc[(c+1)*OBSD + t] * Wfin[c + 1];
        a2 += Wenc[(c+2)*OBSD + t] * Wfin[c + 2];
        a3 += Wenc[(c+3)*OBSD + t] * Wfin[c + 3];
      }
      ws[G_OFF + t] = (a0+a1)+(a2+a3);
    }
  }
}

// ---------------- plane kernel: grid 4096 (b = bid>>5, i0 = (bid&31)*2) ------
__global__ __launch_bounds__(256) void critic_plane(
    const float* __restrict__ obs, const float* __restrict__ pol,
    const float* __restrict__ act, const float* __restrict__ ws,
    float* __restrict__ out)
{
  __shared__ __align__(16) unsigned short s_oa[NN * RSW];   // 18688 B (bf16)
  __shared__ float s_T0[DD], s_T1[DD];
  __shared__ float s_u[DD];
  __shared__ float s_g[OBSD];
  __shared__ float s_dv[NN];
  __shared__ __align__(16) float s_w0[NN], s_w1[NN];
  __shared__ float s_ve[2];

  const int t = threadIdx.x;
  const int b = blockIdx.x >> 5;
  const int i0 = (blockIdx.x & 31) * 2;

  // ---- A: stage oa (bf16), u, g
  {
    const float4* obs4 = (const float4*)(obs + (size_t)b * NN * OBSD);
    #pragma unroll
    for (int k = 0; k < 8; ++k) {
      int idx = t + k * 256;
      float4 v = obs4[idx];
      int row = idx >> 5, c4 = (idx & 31) * 4;
      unsigned* p = (unsigned*)&s_oa[row * RSW + c4];
      p[0] = pack_bf2(v.x, v.y);
      p[1] = pack_bf2(v.z, v.w);
    }
    const float4* act4 = (const float4*)(act + (size_t)b * NN * ACTD);
    float4 a = act4[t];                       // 64 rows x 4 f4 = 256
    int row = t >> 2, t0 = (t & 3) * 4;
    unsigned* p = (unsigned*)&s_oa[row * RSW + OBSD + t0];
    p[0] = pack_bf2(a.x, a.y);
    p[1] = pack_bf2(a.z, a.w);
    // R14 BUG FIX: cooperative strided load (272 elements > 256 threads)
    for (int idx = t; idx < DD + OBSD; idx += 256) {
      if (idx < DD) s_u[idx] = ws[U_OFF + idx];
      else          s_g[idx - DD] = ws[G_OFF + (idx - DD)];
    }
  }
  __syncthreads();

  // ---- B: T_i[e] (threads 0..143) || dv[m] (threads 192..255)
  if (t < DD) {
    float a0 = 0.f, a1 = 0.f;
    const float* mt = ws + t;
    for (int d = 0; d < DD; ++d) {
      float x0 = bf2f(s_oa[i0 * RSW + d]);        // broadcast
      float x1 = bf2f(s_oa[(i0 + 1) * RSW + d]);  // broadcast
      float mv = mt[d * DD];                      // coalesced across e-lanes
      a0 += x0 * mv; a1 += x1 * mv;
    }
    s_T0[t] = a0; s_T1[t] = a1;
  } else if (t >= 192) {
    const int m = t - 192;
    const float* pr = pol + ((size_t)b * NN + m) * ACTD;
    const float* ar = act + ((size_t)b * NN + m) * ACTD;
    float a = 0.f;
    #pragma unroll
    for (int k = 0; k < ACTD; ++k) a += (pr[k] - ar[k]) * s_u[OBSD + k];
    s_dv[m] = a;
  }
  __syncthreads();

  // ---- C: w0,w1,vas (wave0: one LDS read feeds 3 accs) || ve (waves 2,3)
  float sv0 = 0.f, sv1 = 0.f, w0v = 0.f, w1v = 0.f;
  if (t < 64) {
    float a0 = 0.f, a1 = 0.f, av = 0.f;
    for (int e = 0; e < DD; ++e) {
      float x = bf2f(s_oa[t * RSW + e]);          // conflict-free (stride 73 dw)
      a0 += s_T0[e] * x;                          // broadcast
      a1 += s_T1[e] * x;
      av += s_u[e] * x;
    }
    const float kk = 0.08838834764831845f;        // 1/sqrt(128)
    w0v = 1.0f / (1.0f + __expf(-a0 * kk));
    w1v = 1.0f / (1.0f + __expf(-a1 * kk));
    s_w0[t] = w0v; s_w1[t] = w1v;
    float p0 = w0v * av, p1 = w1v * av;
    #pragma unroll
    for (int off = 32; off; off >>= 1) {          // 64-lane butterfly
      p0 += __shfl_xor(p0, off);
      p1 += __shfl_xor(p1, off);
    }
    sv0 = p0; sv1 = p1;                           // full sum in every lane
  } else if (t >= 128 && t < 192) {
    const int l = t - 128;
    float p = bf2f(s_oa[i0 * RSW + l]) * s_g[l]
            + bf2f(s_oa[i0 * RSW + 64 + l]) * s_g[64 + l];
    #pragma unroll
    for (int off = 32; off; off >>= 1) p += __shfl_xor(p, off);
    if (l == 0) s_ve[0] = p;
  } else if (t >= 192) {
    const int l = t - 192;
    float p = bf2f(s_oa[(i0 + 1) * RSW + l]) * s_g[l]
            + bf2f(s_oa[(i0 + 1) * RSW + 64 + l]) * s_g[64 + l];
    #pragma unroll
    for (int off = 32; off; off >>= 1) p += __shfl_xor(p, off);
    if (l == 0) s_ve[1] = p;
  }
  __syncthreads();

  // ---- D: value rows (wave0, from regs) + plane broadcast (all threads)
  if (t < 64) {
    float* valout = out + ((size_t)(b * NN + i0)) * NN;
    valout[t]      = s_ve[0] + (sv0 + w0v * s_dv[t]) * 0.015625f;
    valout[NN + t] = s_ve[1] + (sv1 + w1v * s_dv[t]) * 0.015625f;
  }
  {
    float* w5 = out + (size_t)BB * NN * NN + ((size_t)(b * NN + i0)) * (NN * NN);
    const int m = t >> 4, j4 = t & 15;
    const float4 v0 = *(const float4*)&s_w0[j4 * 4];
    const float4 v1 = *(const float4*)&s_w1[j4 * 4];
    float4* p0 = (float4*)w5;
    float4* p1 = (float4*)(w5 + NN * NN);
    p0[(m +  0) * 16 + j4] = v0;
    p0[(m + 16) * 16 + j4] = v0;
    p0[(m + 32) * 16 + j4] = v0;
    p0[(m + 48) * 16 + j4] = v0;
    p1[(m +  0) * 16 + j4] = v1;
    p1[(m + 16) * 16 + j4] = v1;
    p1[(m + 32) * 16 + j4] = v1;
    p1[(m + 48) * 16 + j4] = v1;
  }
}

extern "C" void kernel_launch(void* const* d_in, const int* in_sizes, int n_in,
                              void* d_out, int out_size, void* d_ws, size_t ws_size,
                              hipStream_t stream) {
  (void)in_sizes; (void)n_in; (void)out_size; (void)ws_size;
  const float* obs  = (const float*)d_in[0];
  const float* pol  = (const float*)d_in[1];
  const float* act  = (const float*)d_in[2];
  const float* Wk   = (const float*)d_in[3];
  const float* Wq   = (const float*)d_in[4];
  const float* Wv   = (const float*)d_in[5];
  const float* Wenc = (const float*)d_in[6];
  const float* Wfin = (const float*)d_in[7];
  float* out = (float*)d_out;
  float* ws  = (float*)d_ws;
  hipLaunchKernelGGL(critic_setup, dim3(DD + 2), dim3(256), 0, stream,
                     Wk, Wq, Wv, Wenc, Wfin, ws);
  hipLaunchKernelGGL(critic_plane, dim3(4096), dim3(256), 0, stream,
                     obs, pol, act, ws, out);
}